// Round 1
// baseline (131.711 us; speedup 1.0000x reference)
//
#include <hip/hip_runtime.h>

// Problem constants (from reference): vol [B=2, 192,192,192, C=1] fp32,
// affine [B,3,4] fp32, output [B,192,192,192,1] fp32.
#define DIM 192
#define NB 2

__global__ __launch_bounds__(DIM) void
SpatialTransformer_warp_kernel(const float* __restrict__ vol,
                               const float* __restrict__ affine,
                               float* __restrict__ out) {
    const int w = threadIdx.x;   // contiguous axis
    const int h = blockIdx.x;
    const int d = blockIdx.y;
    const int b = blockIdx.z;

    const float* __restrict__ A = affine + b * 12;
    const float a00 = A[0], a01 = A[1], a02 = A[2],  a03 = A[3];
    const float a10 = A[4], a11 = A[5], a12 = A[6],  a13 = A[7];
    const float a20 = A[8], a21 = A[9], a22 = A[10], a23 = A[11];

    const float center = (DIM - 1) * 0.5f;   // 95.5
    const float maxl   = (float)(DIM - 1);   // 191

    const float cd = (float)d - center;
    const float ch = (float)h - center;
    const float cw = (float)w - center;

    // loc = A*[centered;1] + center  (mesh + shift collapses to this)
    const float ld = a00 * cd + a01 * ch + a02 * cw + a03 + center;
    const float lh = a10 * cd + a11 * ch + a12 * cw + a13 + center;
    const float lw = a20 * cd + a21 * ch + a22 * cw + a23 + center;

    // Per-axis: cl = clip(loc,0,max); l0 = clip(floor(loc),0,max); l1 = min(l0+1,max)
    // weight for floor corner: w0 = l1 - cl ; ceil corner: w1 = 1 - w0.
    float cl, l0f, l1f;

    cl  = fminf(fmaxf(ld, 0.0f), maxl);
    l0f = fminf(fmaxf(floorf(ld), 0.0f), maxl);
    l1f = fminf(l0f + 1.0f, maxl);
    const float w0d = l1f - cl, w1d = 1.0f - w0d;
    const int i0d = (int)l0f, i1d = (int)l1f;

    cl  = fminf(fmaxf(lh, 0.0f), maxl);
    l0f = fminf(fmaxf(floorf(lh), 0.0f), maxl);
    l1f = fminf(l0f + 1.0f, maxl);
    const float w0h = l1f - cl, w1h = 1.0f - w0h;
    const int i0h = (int)l0f, i1h = (int)l1f;

    cl  = fminf(fmaxf(lw, 0.0f), maxl);
    l0f = fminf(fmaxf(floorf(lw), 0.0f), maxl);
    l1f = fminf(l0f + 1.0f, maxl);
    const float w0w = l1f - cl, w1w = 1.0f - w0w;
    const int i0w = (int)l0f, i1w = (int)l1f;

    const size_t plane = (size_t)DIM * DIM;
    const float* __restrict__ vb = vol + (size_t)b * DIM * plane;

    const float* r00 = vb + (size_t)i0d * plane + (size_t)i0h * DIM;
    const float* r01 = vb + (size_t)i0d * plane + (size_t)i1h * DIM;
    const float* r10 = vb + (size_t)i1d * plane + (size_t)i0h * DIM;
    const float* r11 = vb + (size_t)i1d * plane + (size_t)i1h * DIM;

    const float v000 = r00[i0w], v001 = r00[i1w];
    const float v010 = r01[i0w], v011 = r01[i1w];
    const float v100 = r10[i0w], v101 = r10[i1w];
    const float v110 = r11[i0w], v111 = r11[i1w];

    const float x00 = v000 * w0w + v001 * w1w;
    const float x01 = v010 * w0w + v011 * w1w;
    const float x10 = v100 * w0w + v101 * w1w;
    const float x11 = v110 * w0w + v111 * w1w;

    const float y0 = x00 * w0h + x01 * w1h;
    const float y1 = x10 * w0h + x11 * w1h;

    const float res = y0 * w0d + y1 * w1d;

    out[((size_t)b * DIM + d) * plane + (size_t)h * DIM + w] = res;
}

extern "C" void kernel_launch(void* const* d_in, const int* in_sizes, int n_in,
                              void* d_out, int out_size, void* d_ws, size_t ws_size,
                              hipStream_t stream) {
    const float* vol    = (const float*)d_in[0];
    const float* affine = (const float*)d_in[1];
    float* out = (float*)d_out;

    dim3 grid(DIM, DIM, NB);   // (h, d, b)
    dim3 block(DIM);           // w
    SpatialTransformer_warp_kernel<<<grid, block, 0, stream>>>(vol, affine, out);
}

// Round 2
// 128.045 us; speedup vs baseline: 1.0286x; 1.0286x over previous
//
#include <hip/hip_runtime.h>

// vol [B=2, 192,192,192, C=1] fp32, affine [B,3,4] fp32,
// out [B,192,192,192,1] fp32.
#define DIM 192
#define NB 2
#define HPT 2   // h-voxels per thread

__global__ __launch_bounds__(DIM) void
SpatialTransformer_warp_kernel(const float* __restrict__ vol,
                               const float* __restrict__ affine,
                               float* __restrict__ out) {
    const int w  = threadIdx.x;          // contiguous axis
    const int h0 = blockIdx.x * HPT;     // h, h+1
    const int d  = blockIdx.y;
    const int b  = blockIdx.z;

    const float* __restrict__ A = affine + b * 12;
    const float a00 = A[0], a01 = A[1], a02 = A[2],  a03 = A[3];
    const float a10 = A[4], a11 = A[5], a12 = A[6],  a13 = A[7];
    const float a20 = A[8], a21 = A[9], a22 = A[10], a23 = A[11];

    const float center = (DIM - 1) * 0.5f;   // 95.5
    const float maxl   = (float)(DIM - 1);   // 191

    const float cd = (float)d - center;
    const float cw = (float)w - center;

    // Partial sums independent of h
    const float pd = a00 * cd + a02 * cw + a03 + center;
    const float ph = a10 * cd + a12 * cw + a13 + center;
    const float pw = a20 * cd + a22 * cw + a23 + center;

    const int   plane = DIM * DIM;
    const float* __restrict__ vb = vol + (size_t)b * DIM * plane;
    float* __restrict__ ob = out + ((size_t)b * DIM + d) * plane + w;

    // Per-voxel state for the pair
    float vals[HPT][8];
    float w0d_[HPT], w0h_[HPT], w0w_[HPT];

#pragma unroll
    for (int k = 0; k < HPT; ++k) {
        const float ch = (float)(h0 + k) - center;
        const float ld = a01 * ch + pd;
        const float lh = a11 * ch + ph;
        const float lw = a21 * ch + pw;

        float cl, l0f, l1f;

        cl  = fminf(fmaxf(ld, 0.0f), maxl);
        l0f = fminf(fmaxf(floorf(ld), 0.0f), maxl);
        l1f = fminf(l0f + 1.0f, maxl);
        w0d_[k] = l1f - cl;
        const int i0d = (int)l0f, i1d = (int)l1f;

        cl  = fminf(fmaxf(lh, 0.0f), maxl);
        l0f = fminf(fmaxf(floorf(lh), 0.0f), maxl);
        l1f = fminf(l0f + 1.0f, maxl);
        w0h_[k] = l1f - cl;
        const int i0h = (int)l0f, i1h = (int)l1f;

        cl  = fminf(fmaxf(lw, 0.0f), maxl);
        l0f = fminf(fmaxf(floorf(lw), 0.0f), maxl);
        l1f = fminf(l0f + 1.0f, maxl);
        w0w_[k] = l1f - cl;
        const int i0w = (int)l0f, i1w = (int)l1f;

        const int b00 = i0d * plane + i0h * DIM;
        const int b01 = i0d * plane + i1h * DIM;
        const int b10 = i1d * plane + i0h * DIM;
        const int b11 = i1d * plane + i1h * DIM;

        // Issue all 8 gathers; no use until the blend below.
        vals[k][0] = vb[b00 + i0w];
        vals[k][1] = vb[b00 + i1w];
        vals[k][2] = vb[b01 + i0w];
        vals[k][3] = vb[b01 + i1w];
        vals[k][4] = vb[b10 + i0w];
        vals[k][5] = vb[b10 + i1w];
        vals[k][6] = vb[b11 + i0w];
        vals[k][7] = vb[b11 + i1w];
    }

#pragma unroll
    for (int k = 0; k < HPT; ++k) {
        const float w0w = w0w_[k], w1w = 1.0f - w0w;
        const float w0h = w0h_[k], w1h = 1.0f - w0h;
        const float w0d = w0d_[k], w1d = 1.0f - w0d;

        const float x00 = vals[k][0] * w0w + vals[k][1] * w1w;
        const float x01 = vals[k][2] * w0w + vals[k][3] * w1w;
        const float x10 = vals[k][4] * w0w + vals[k][5] * w1w;
        const float x11 = vals[k][6] * w0w + vals[k][7] * w1w;

        const float y0 = x00 * w0h + x01 * w1h;
        const float y1 = x10 * w0h + x11 * w1h;

        __builtin_nontemporal_store(y0 * w0d + y1 * w1d, ob + (h0 + k) * DIM);
    }
}

extern "C" void kernel_launch(void* const* d_in, const int* in_sizes, int n_in,
                              void* d_out, int out_size, void* d_ws, size_t ws_size,
                              hipStream_t stream) {
    const float* vol    = (const float*)d_in[0];
    const float* affine = (const float*)d_in[1];
    float* out = (float*)d_out;

    dim3 grid(DIM / HPT, DIM, NB);   // (h-pair, d, b)
    dim3 block(DIM);                 // w
    SpatialTransformer_warp_kernel<<<grid, block, 0, stream>>>(vol, affine, out);
}

// Round 3
// 126.769 us; speedup vs baseline: 1.0390x; 1.0101x over previous
//
#include <hip/hip_runtime.h>

// vol [B=2, 192,192,192, C=1] fp32, affine [B,3,4] fp32,
// out [B,192,192,192,1] fp32.
#define DIM 192
#define NB 2
#define HPT 2   // h-voxels per thread

// 4-byte-aligned float2: lets the compiler emit dwordx2 if unaligned global
// access is available, else two dword loads sharing one address register.
typedef float f2 __attribute__((ext_vector_type(2), aligned(4)));

__global__ __launch_bounds__(DIM) void
SpatialTransformer_warp_kernel(const float* __restrict__ vol,
                               const float* __restrict__ affine,
                               float* __restrict__ out) {
    const int w  = threadIdx.x;          // contiguous axis
    const int h0 = blockIdx.x * HPT;     // h, h+1
    const int d  = blockIdx.y;
    const int b  = blockIdx.z;

    const float* __restrict__ A = affine + b * 12;
    const float a00 = A[0], a01 = A[1], a02 = A[2],  a03 = A[3];
    const float a10 = A[4], a11 = A[5], a12 = A[6],  a13 = A[7];
    const float a20 = A[8], a21 = A[9], a22 = A[10], a23 = A[11];

    const float center = (DIM - 1) * 0.5f;   // 95.5
    const float maxl   = (float)(DIM - 1);   // 191.0
    const float maxi0  = (float)(DIM - 2);   // 190.0

    const float cd = (float)d - center;
    const float cw = (float)w - center;

    // Partial sums independent of h
    const float pd = a00 * cd + a02 * cw + a03 + center;
    const float ph = a10 * cd + a12 * cw + a13 + center;
    const float pw = a20 * cd + a22 * cw + a23 + center;

    const int plane = DIM * DIM;
    const float* __restrict__ vb = vol + (size_t)b * DIM * plane;
    float* __restrict__ ob = out + ((size_t)b * DIM + d) * plane + w;

    f2 r00[HPT], r01[HPT], r10[HPT], r11[HPT];
    float w0d_[HPT], w0h_[HPT], w0w_[HPT];

#pragma unroll
    for (int k = 0; k < HPT; ++k) {
        const float ch = (float)(h0 + k) - center;
        const float ld = a01 * ch + pd;
        const float lh = a11 * ch + ph;
        const float lw = a21 * ch + pw;

        // i0 = min(floor(clamp(l,0,191)), 190); i1 = i0+1 (always in range);
        // w0 = (i0+1) - clamp(l,0,191)  — identical to reference semantics.
        const float td = __builtin_amdgcn_fmed3f(ld, 0.0f, maxl);
        const float th = __builtin_amdgcn_fmed3f(lh, 0.0f, maxl);
        const float tw = __builtin_amdgcn_fmed3f(lw, 0.0f, maxl);

        const float fd = fminf(floorf(td), maxi0);
        const float fh = fminf(floorf(th), maxi0);
        const float fw = fminf(floorf(tw), maxi0);

        w0d_[k] = fd + 1.0f - td;
        w0h_[k] = fh + 1.0f - th;
        w0w_[k] = fw + 1.0f - tw;

        const int i0d = (int)fd;
        const int i0h = (int)fh;
        const int i0w = (int)fw;

        const int idx = __umul24(i0d, plane) + __umul24(i0h, DIM) + i0w;
        const float* p = vb + idx;

        r00[k] = *(const f2*)(p);                 // (i0d, i0h, i0w..i0w+1)
        r01[k] = *(const f2*)(p + DIM);           // (i0d, i0h+1, ...)
        r10[k] = *(const f2*)(p + plane);         // (i0d+1, i0h, ...)
        r11[k] = *(const f2*)(p + plane + DIM);   // (i0d+1, i0h+1, ...)
    }

#pragma unroll
    for (int k = 0; k < HPT; ++k) {
        const float w0w = w0w_[k], w1w = 1.0f - w0w;
        const float w0h = w0h_[k], w1h = 1.0f - w0h;
        const float w0d = w0d_[k], w1d = 1.0f - w0d;

        const float x00 = r00[k].x * w0w + r00[k].y * w1w;
        const float x01 = r01[k].x * w0w + r01[k].y * w1w;
        const float x10 = r10[k].x * w0w + r10[k].y * w1w;
        const float x11 = r11[k].x * w0w + r11[k].y * w1w;

        const float y0 = x00 * w0h + x01 * w1h;
        const float y1 = x10 * w0h + x11 * w1h;

        __builtin_nontemporal_store(y0 * w0d + y1 * w1d, ob + (h0 + k) * DIM);
    }
}

extern "C" void kernel_launch(void* const* d_in, const int* in_sizes, int n_in,
                              void* d_out, int out_size, void* d_ws, size_t ws_size,
                              hipStream_t stream) {
    const float* vol    = (const float*)d_in[0];
    const float* affine = (const float*)d_in[1];
    float* out = (float*)d_out;

    dim3 grid(DIM / HPT, DIM, NB);   // (h-pair, d, b)
    dim3 block(DIM);                 // w
    SpatialTransformer_warp_kernel<<<grid, block, 0, stream>>>(vol, affine, out);
}

// Round 4
// 125.631 us; speedup vs baseline: 1.0484x; 1.0091x over previous
//
#include <hip/hip_runtime.h>

// vol [B=2, 192,192,192, C=1] fp32, affine [B,3,4] fp32,
// out [B,192,192,192,1] fp32.
#define DIM 192
#define NB 2
#define HPT 4   // h-voxels per thread

typedef float f2 __attribute__((ext_vector_type(2), aligned(4)));

__global__ __launch_bounds__(DIM) void
SpatialTransformer_warp_kernel(const float* __restrict__ vol,
                               const float* __restrict__ affine,
                               float* __restrict__ out) {
    const int w  = threadIdx.x;          // contiguous axis
    const int h0 = blockIdx.x * HPT;     // h .. h+3
    const int d  = blockIdx.y;
    const int b  = blockIdx.z;

    const float* __restrict__ A = affine + b * 12;
    const float a00 = A[0], a01 = A[1], a02 = A[2],  a03 = A[3];
    const float a10 = A[4], a11 = A[5], a12 = A[6],  a13 = A[7];
    const float a20 = A[8], a21 = A[9], a22 = A[10], a23 = A[11];

    const float center = (DIM - 1) * 0.5f;   // 95.5
    const float maxl   = (float)(DIM - 1);   // 191.0
    const float maxi0  = (float)(DIM - 2);   // 190.0
    const float fplane = (float)(DIM * DIM); // 36864.0
    const float fdim   = (float)DIM;         // 192.0

    const float cd = (float)d - center;
    const float cw = (float)w - center;

    // Partial sums independent of h
    const float pd = a00 * cd + a02 * cw + a03 + center;
    const float ph = a10 * cd + a12 * cw + a13 + center;
    const float pw = a20 * cd + a22 * cw + a23 + center;

    const int plane = DIM * DIM;
    const float* __restrict__ vb = vol + (size_t)b * DIM * plane;
    float* __restrict__ ob = out + ((size_t)b * DIM + d) * plane + w;

    f2 r00[HPT], r01[HPT], r10[HPT], r11[HPT];
    float w0d_[HPT], w0h_[HPT], w0w_[HPT];

#pragma unroll
    for (int k = 0; k < HPT; ++k) {
        const float ch = (float)(h0 + k) - center;
        const float ld = a01 * ch + pd;
        const float lh = a11 * ch + ph;
        const float lw = a21 * ch + pw;

        // i0 = min(floor(clamp(l,0,191)),190); i1 = i0+1; w0 = i0+1 - clamp(l).
        // Identical to reference semantics (right-clamp corner has zero weight).
        const float td = __builtin_amdgcn_fmed3f(ld, 0.0f, maxl);
        const float th = __builtin_amdgcn_fmed3f(lh, 0.0f, maxl);
        const float tw = __builtin_amdgcn_fmed3f(lw, 0.0f, maxl);

        const float fd = fminf(floorf(td), maxi0);
        const float fh = fminf(floorf(th), maxi0);
        const float fw = fminf(floorf(tw), maxi0);

        w0d_[k] = fd + 1.0f - td;
        w0h_[k] = fh + 1.0f - th;
        w0w_[k] = fw + 1.0f - tw;

        // Flat index in float: all values integer-valued and < 2^24 → exact.
        const int idx = (int)__builtin_fmaf(fd, fplane, __builtin_fmaf(fh, fdim, fw));
        const float* p = vb + idx;

        r00[k] = *(const f2*)(p);                 // (d0, h0, w0..w0+1)
        r01[k] = *(const f2*)(p + DIM);           // (d0, h0+1)
        r10[k] = *(const f2*)(p + plane);         // (d0+1, h0)
        r11[k] = *(const f2*)(p + plane + DIM);   // (d0+1, h0+1)
    }

#pragma unroll
    for (int k = 0; k < HPT; ++k) {
        const float w0w = w0w_[k], w1w = 1.0f - w0w;
        const float w0h = w0h_[k], w1h = 1.0f - w0h;
        const float w0d = w0d_[k], w1d = 1.0f - w0d;

        const float x00 = r00[k].x * w0w + r00[k].y * w1w;
        const float x01 = r01[k].x * w0w + r01[k].y * w1w;
        const float x10 = r10[k].x * w0w + r10[k].y * w1w;
        const float x11 = r11[k].x * w0w + r11[k].y * w1w;

        const float y0 = x00 * w0h + x01 * w1h;
        const float y1 = x10 * w0h + x11 * w1h;

        __builtin_nontemporal_store(y0 * w0d + y1 * w1d, ob + (h0 + k) * DIM);
    }
}

extern "C" void kernel_launch(void* const* d_in, const int* in_sizes, int n_in,
                              void* d_out, int out_size, void* d_ws, size_t ws_size,
                              hipStream_t stream) {
    const float* vol    = (const float*)d_in[0];
    const float* affine = (const float*)d_in[1];
    float* out = (float*)d_out;

    dim3 grid(DIM / HPT, DIM, NB);   // (h-quad, d, b)
    dim3 block(DIM);                 // w
    SpatialTransformer_warp_kernel<<<grid, block, 0, stream>>>(vol, affine, out);
}